// Round 1
// baseline (350.867 us; speedup 1.0000x reference)
//
#include <hip/hip_runtime.h>

typedef __attribute__((ext_vector_type(8))) short short8;
typedef __attribute__((ext_vector_type(4))) float f32x4;

#define BM 128
#define BN 128
#define BK 32
#define INF 4096

__device__ __forceinline__ unsigned short f2bf(float f) {
    unsigned int u = __float_as_uint(f);
    u += 0x7FFFu + ((u >> 16) & 1u);
    return (unsigned short)(u >> 16);
}

__global__ __launch_bounds__(256)
void hcl_mfma(const float* __restrict__ x,
              const float* __restrict__ hw,
              const float* __restrict__ hb,
              float* __restrict__ out)
{
    __shared__ unsigned short As[BM][BK];
    __shared__ unsigned short Bs[BN][BK];

    const int tid  = threadIdx.x;
    const int lane = tid & 63;
    const int wave = tid >> 6;
    const int wr   = wave >> 1, wc = wave & 1;

    const int bm0 = blockIdx.x * BM;
    const int p   = blockIdx.y >> 1;
    const int nh  = blockIdx.y & 1;

    f32x4 acc[4][4] = {};

    const int srow = tid >> 3;        // 0..31
    const int scol = (tid & 7) * 4;   // 0,4,..,28

    // K loop: 5 chunks (t) x 8 k-tiles of 32. t unrolled -> compile-time masks.
    #pragma unroll
    for (int t = 0; t < 5; ++t) {
        const int mask = (t == 0) ? 0 : (1 << (t - 1));
        const int s = p ^ mask;
        const float* xchunk = x  + (size_t)bm0 * INF + s * 256;
        const float* wchunk = hw + ((size_t)(t * 16 + s) * 256 + nh * 128) * 256;

        for (int k8 = 0; k8 < 8; ++k8) {
            const int kc = k8 * BK;

            #pragma unroll
            for (int i = 0; i < 4; ++i) {
                const int row = i * 32 + srow;
                float4 fa = *(const float4*)(xchunk + (size_t)row * INF + kc + scol);
                float4 fb = *(const float4*)(wchunk + (size_t)row * 256 + kc + scol);
                ushort4 ua, ub;
                ua.x = f2bf(fa.x); ua.y = f2bf(fa.y);
                ua.z = f2bf(fa.z); ua.w = f2bf(fa.w);
                ub.x = f2bf(fb.x); ub.y = f2bf(fb.y);
                ub.z = f2bf(fb.z); ub.w = f2bf(fb.w);
                *(ushort4*)&As[row][scol] = ua;
                *(ushort4*)&Bs[row][scol] = ub;
            }
            __syncthreads();

            short8 a[4], b[4];
            #pragma unroll
            for (int mi = 0; mi < 4; ++mi)
                a[mi] = *(const short8*)&As[wr * 64 + mi * 16 + (lane & 15)][(lane >> 4) * 8];
            #pragma unroll
            for (int nj = 0; nj < 4; ++nj)
                b[nj] = *(const short8*)&Bs[wc * 64 + nj * 16 + (lane & 15)][(lane >> 4) * 8];

            #pragma unroll
            for (int mi = 0; mi < 4; ++mi)
                #pragma unroll
                for (int nj = 0; nj < 4; ++nj)
                    acc[mi][nj] = __builtin_amdgcn_mfma_f32_16x16x32_bf16(
                        a[mi], b[nj], acc[mi][nj], 0, 0, 0);

            __syncthreads();
        }
    }

    // Epilogue: C/D layout col = lane&15, row = (lane>>4)*4 + r  [m89-verified]
    const int col0 = p * 256 + nh * 128 + wc * 64;
    #pragma unroll
    for (int nj = 0; nj < 4; ++nj) {
        const int col = col0 + nj * 16 + (lane & 15);
        const float bias = hb[col];
        #pragma unroll
        for (int mi = 0; mi < 4; ++mi) {
            #pragma unroll
            for (int r = 0; r < 4; ++r) {
                const int row = bm0 + wr * 64 + mi * 16 + (lane >> 4) * 4 + r;
                out[(size_t)row * 4096 + col] = acc[mi][nj][r] + bias;
            }
        }
    }
}

extern "C" void kernel_launch(void* const* d_in, const int* in_sizes, int n_in,
                              void* d_out, int out_size, void* d_ws, size_t ws_size,
                              hipStream_t stream) {
    const float* x  = (const float*)d_in[0];   // [8192, 4096]
    const float* hw = (const float*)d_in[1];   // [5, 16, 256, 256]
    const float* hb = (const float*)d_in[2];   // [4096]
    float* out = (float*)d_out;                // [8192, 4096]

    dim3 grid(8192 / BM, 32);  // x: m-tiles; y: p (16) * n-half (2)
    hcl_mfma<<<grid, 256, 0, stream>>>(x, hw, hb, out);
}

// Round 2
// 169.246 us; speedup vs baseline: 2.0731x; 2.0731x over previous
//
#include <hip/hip_runtime.h>

typedef __attribute__((ext_vector_type(8))) short short8;
typedef __attribute__((ext_vector_type(4))) float f32x4;

#define BM 128
#define BN 128
#define BK 32
#define INF 4096

#define AS1 __attribute__((address_space(1)))
#define AS3 __attribute__((address_space(3)))

__device__ __forceinline__ unsigned short f2bf(float f) {
    unsigned int u = __float_as_uint(f);
    u += 0x7FFFu + ((u >> 16) & 1u);
    return (unsigned short)(u >> 16);
}

__device__ __forceinline__ void gl_lds16(const unsigned short* g, unsigned short* l) {
    __builtin_amdgcn_global_load_lds((const AS1 void*)g, (AS3 void*)l, 16, 0, 0);
}

// ---------------- prepass: fp32 -> bf16 for x and hw ----------------
__global__ __launch_bounds__(256)
void cvt_bf16(const float* __restrict__ x, const float* __restrict__ hw,
              unsigned short* __restrict__ xb, unsigned short* __restrict__ wb)
{
    const long long NX = 8192LL * 4096;
    const long long NW = 5LL * 16 * 256 * 256;
    const long long total8 = (NX + NW) / 8;
    for (long long i = (long long)blockIdx.x * 256 + threadIdx.x; i < total8;
         i += (long long)gridDim.x * 256) {
        long long e = i * 8;
        const float* src;
        unsigned short* dst;
        long long off;
        if (e < NX) { src = x;  dst = xb; off = e; }
        else        { src = hw; dst = wb; off = e - NX; }
        float4 f0 = *(const float4*)(src + off);
        float4 f1 = *(const float4*)(src + off + 4);
        ushort4 u0, u1;
        u0.x = f2bf(f0.x); u0.y = f2bf(f0.y); u0.z = f2bf(f0.z); u0.w = f2bf(f0.w);
        u1.x = f2bf(f1.x); u1.y = f2bf(f1.y); u1.z = f2bf(f1.z); u1.w = f2bf(f1.w);
        *(ushort4*)(dst + off)     = u0;
        *(ushort4*)(dst + off + 4) = u1;
    }
}

// ---------------- main GEMM: bf16 inputs, global_load_lds staging ----------------
__global__ __launch_bounds__(256)
void hcl_gemm(const unsigned short* __restrict__ xb,
              const unsigned short* __restrict__ wb,
              const float* __restrict__ hb,
              float* __restrict__ out)
{
    __shared__ unsigned short As[BM][BK];   // 8 KB
    __shared__ unsigned short Bs[BN][BK];   // 8 KB

    const int tid  = threadIdx.x;
    const int lane = tid & 63;
    const int wave = tid >> 6;
    const int wr   = wave >> 1, wc = wave & 1;

    const int bm0 = blockIdx.x * BM;
    const int p   = blockIdx.y >> 1;
    const int nh  = blockIdx.y & 1;

    f32x4 acc[4][4] = {};

    // staging geometry: 256 threads x 16B covers 64 rows of 64B (BK=32 bf16).
    // LDS dest is wave-uniform base (wave w -> rows w*16..w*16+15), lane scatter
    // is linear: lane l -> row w*16 + (l>>2), col (l&3)*8.  [m97 pattern]
    const int srow = tid >> 2;          // 0..63
    const int scol = (lane & 3) * 8;    // bf16 elems
    unsigned short* ldsA0 = &As[wave * 16][0];
    unsigned short* ldsA1 = &As[64 + wave * 16][0];
    unsigned short* ldsB0 = &Bs[wave * 16][0];
    unsigned short* ldsB1 = &Bs[64 + wave * 16][0];

    #pragma unroll
    for (int t = 0; t < 5; ++t) {
        const int mask = (t == 0) ? 0 : (1 << (t - 1));
        const int s = p ^ mask;
        const unsigned short* xc = xb + (size_t)bm0 * INF + s * 256;
        const unsigned short* wc_ = wb + ((size_t)(t * 16 + s) * 256 + nh * 128) * 256;

        for (int k8 = 0; k8 < 8; ++k8) {
            const int kc = k8 * BK;

            gl_lds16(xc  + (size_t)srow        * INF + kc + scol, ldsA0);
            gl_lds16(xc  + (size_t)(64 + srow) * INF + kc + scol, ldsA1);
            gl_lds16(wc_ + (size_t)srow        * 256 + kc + scol, ldsB0);
            gl_lds16(wc_ + (size_t)(64 + srow) * 256 + kc + scol, ldsB1);

            __syncthreads();

            short8 a[4], b[4];
            #pragma unroll
            for (int mi = 0; mi < 4; ++mi)
                a[mi] = *(const short8*)&As[wr * 64 + mi * 16 + (lane & 15)][(lane >> 4) * 8];
            #pragma unroll
            for (int nj = 0; nj < 4; ++nj)
                b[nj] = *(const short8*)&Bs[wc * 64 + nj * 16 + (lane & 15)][(lane >> 4) * 8];

            #pragma unroll
            for (int mi = 0; mi < 4; ++mi)
                #pragma unroll
                for (int nj = 0; nj < 4; ++nj)
                    acc[mi][nj] = __builtin_amdgcn_mfma_f32_16x16x32_bf16(
                        a[mi], b[nj], acc[mi][nj], 0, 0, 0);

            __syncthreads();
        }
    }

    // Epilogue: C/D layout col = lane&15, row = (lane>>4)*4 + r  [m89-verified]
    const int col0 = p * 256 + nh * 128 + wc * 64;
    #pragma unroll
    for (int nj = 0; nj < 4; ++nj) {
        const int col = col0 + nj * 16 + (lane & 15);
        const float bias = hb[col];
        #pragma unroll
        for (int mi = 0; mi < 4; ++mi) {
            #pragma unroll
            for (int r = 0; r < 4; ++r) {
                const int row = bm0 + wr * 64 + mi * 16 + (lane >> 4) * 4 + r;
                out[(size_t)row * 4096 + col] = acc[mi][nj][r] + bias;
            }
        }
    }
}

// ---------------- fallback (round-1 fused kernel) if ws too small ----------------
__global__ __launch_bounds__(256)
void hcl_mfma_fused(const float* __restrict__ x,
                    const float* __restrict__ hw,
                    const float* __restrict__ hb,
                    float* __restrict__ out)
{
    __shared__ unsigned short As[BM][BK];
    __shared__ unsigned short Bs[BN][BK];

    const int tid  = threadIdx.x;
    const int lane = tid & 63;
    const int wave = tid >> 6;
    const int wr   = wave >> 1, wc = wave & 1;

    const int bm0 = blockIdx.x * BM;
    const int p   = blockIdx.y >> 1;
    const int nh  = blockIdx.y & 1;

    f32x4 acc[4][4] = {};

    const int srow = tid >> 3;
    const int scol = (tid & 7) * 4;

    #pragma unroll
    for (int t = 0; t < 5; ++t) {
        const int mask = (t == 0) ? 0 : (1 << (t - 1));
        const int s = p ^ mask;
        const float* xchunk = x  + (size_t)bm0 * INF + s * 256;
        const float* wchunk = hw + ((size_t)(t * 16 + s) * 256 + nh * 128) * 256;

        for (int k8 = 0; k8 < 8; ++k8) {
            const int kc = k8 * BK;
            #pragma unroll
            for (int i = 0; i < 4; ++i) {
                const int row = i * 32 + srow;
                float4 fa = *(const float4*)(xchunk + (size_t)row * INF + kc + scol);
                float4 fb = *(const float4*)(wchunk + (size_t)row * 256 + kc + scol);
                ushort4 ua, ub;
                ua.x = f2bf(fa.x); ua.y = f2bf(fa.y);
                ua.z = f2bf(fa.z); ua.w = f2bf(fa.w);
                ub.x = f2bf(fb.x); ub.y = f2bf(fb.y);
                ub.z = f2bf(fb.z); ub.w = f2bf(fb.w);
                *(ushort4*)&As[row][scol] = ua;
                *(ushort4*)&Bs[row][scol] = ub;
            }
            __syncthreads();

            short8 a[4], b[4];
            #pragma unroll
            for (int mi = 0; mi < 4; ++mi)
                a[mi] = *(const short8*)&As[wr * 64 + mi * 16 + (lane & 15)][(lane >> 4) * 8];
            #pragma unroll
            for (int nj = 0; nj < 4; ++nj)
                b[nj] = *(const short8*)&Bs[wc * 64 + nj * 16 + (lane & 15)][(lane >> 4) * 8];

            #pragma unroll
            for (int mi = 0; mi < 4; ++mi)
                #pragma unroll
                for (int nj = 0; nj < 4; ++nj)
                    acc[mi][nj] = __builtin_amdgcn_mfma_f32_16x16x32_bf16(
                        a[mi], b[nj], acc[mi][nj], 0, 0, 0);

            __syncthreads();
        }
    }

    const int col0 = p * 256 + nh * 128 + wc * 64;
    #pragma unroll
    for (int nj = 0; nj < 4; ++nj) {
        const int col = col0 + nj * 16 + (lane & 15);
        const float bias = hb[col];
        #pragma unroll
        for (int mi = 0; mi < 4; ++mi) {
            #pragma unroll
            for (int r = 0; r < 4; ++r) {
                const int row = bm0 + wr * 64 + mi * 16 + (lane >> 4) * 4 + r;
                out[(size_t)row * 4096 + col] = acc[mi][nj][r] + bias;
            }
        }
    }
}

extern "C" void kernel_launch(void* const* d_in, const int* in_sizes, int n_in,
                              void* d_out, int out_size, void* d_ws, size_t ws_size,
                              hipStream_t stream) {
    const float* x  = (const float*)d_in[0];   // [8192, 4096]
    const float* hw = (const float*)d_in[1];   // [5, 16, 256, 256]
    const float* hb = (const float*)d_in[2];   // [4096]
    float* out = (float*)d_out;                // [8192, 4096]

    const size_t NX = 8192ull * 4096;
    const size_t NW = 5ull * 16 * 256 * 256;
    const size_t need = (NX + NW) * sizeof(unsigned short);

    if (ws_size >= need) {
        unsigned short* xb = (unsigned short*)d_ws;
        unsigned short* wb = xb + NX;
        cvt_bf16<<<2048, 256, 0, stream>>>(x, hw, xb, wb);
        dim3 grid(8192 / BM, 32);
        hcl_gemm<<<grid, 256, 0, stream>>>(xb, wb, hb, out);
    } else {
        dim3 grid(8192 / BM, 32);
        hcl_mfma_fused<<<grid, 256, 0, stream>>>(x, hw, hb, out);
    }
}

// Round 4
// 154.390 us; speedup vs baseline: 2.2726x; 1.0962x over previous
//
#include <hip/hip_runtime.h>

typedef __attribute__((ext_vector_type(8))) short short8;
typedef __attribute__((ext_vector_type(4))) float f32x4;

#define INF 4096
#define NKT 40              // 5 chunks * 8 K-tiles of 32  (K = 5*256 = 1280)
#define BUFB 32768          // bytes per K-tile buffer (A 16KB + B 16KB)

#define AS1 __attribute__((address_space(1)))
#define AS3 __attribute__((address_space(3)))

__device__ __forceinline__ unsigned short f2bf(float f) {
    unsigned int u = __float_as_uint(f);
    u += 0x7FFFu + ((u >> 16) & 1u);
    return (unsigned short)(u >> 16);
}

__device__ __forceinline__ void gl_lds16(const unsigned short* g, void* l) {
    __builtin_amdgcn_global_load_lds((const AS1 void*)g, (AS3 void*)l, 16, 0, 0);
}

// swizzle within a 16KB [256][32]-bf16 tile (64B rows): XOR byte bits {4,5}
// with row bits {1,2}. Involution, preserves 16B alignment. Fragment reads
// (stride-64B, 16 rows per lane-quad) then walk all 32 banks per 8 rows.
__device__ __forceinline__ int swz(int b) { return b ^ ((b >> 3) & 0x30); }

// ---------------- prepass: fp32 -> bf16 for x and hw ----------------
__global__ __launch_bounds__(256)
void cvt_bf16(const float* __restrict__ x, const float* __restrict__ hw,
              unsigned short* __restrict__ xb, unsigned short* __restrict__ wb)
{
    const long long NX = 8192LL * 4096;
    const long long NW = 5LL * 16 * 256 * 256;
    const long long total8 = (NX + NW) / 8;
    for (long long i = (long long)blockIdx.x * 256 + threadIdx.x; i < total8;
         i += (long long)gridDim.x * 256) {
        long long e = i * 8;
        const float* src;
        unsigned short* dst;
        long long off;
        if (e < NX) { src = x;  dst = xb; off = e; }
        else        { src = hw; dst = wb; off = e - NX; }
        float4 f0 = *(const float4*)(src + off);
        float4 f1 = *(const float4*)(src + off + 4);
        ushort4 u0, u1;
        u0.x = f2bf(f0.x); u0.y = f2bf(f0.y); u0.z = f2bf(f0.z); u0.w = f2bf(f0.w);
        u1.x = f2bf(f1.x); u1.y = f2bf(f1.y); u1.z = f2bf(f1.z); u1.w = f2bf(f1.w);
        *(ushort4*)(dst + off)     = u0;
        *(ushort4*)(dst + off + 4) = u1;
    }
}

// ---------------- main GEMM: 256x256 tile, 3-buffer counted-vmcnt pipeline ----------------
__global__ __launch_bounds__(512, 2)
void hcl_gemm8(const unsigned short* __restrict__ xb,
               const unsigned short* __restrict__ wb,
               const float* __restrict__ hb,
               float* __restrict__ out)
{
    extern __shared__ unsigned short lds[];   // 3 * 32KB

    const int tid  = threadIdx.x;
    const int lane = tid & 63;
    const int wave = tid >> 6;
    const int wr   = wave >> 2;     // 0..1  (m-half of tile)
    const int wcn  = wave & 3;      // 0..3  (n-quarter of tile)
    const int ln15 = lane & 15;
    const int hi   = lane >> 4;     // 0..3

    const int bm0 = blockIdx.x * 256;
    const int p   = blockIdx.y;     // 0..15

    // ---- staging geometry (per-thread constants) ----
    // linear LDS byte for inst l: b = (l*512 + tid)*16 ; data at logical swz(b)
    const int b0 = tid * 16;
    const int b1 = (512 + tid) * 16;
    const int g0 = swz(b0), g1 = swz(b1);
    const int rS0 = g0 >> 6, cS0 = (g0 & 63) >> 1;
    const int rS1 = g1 >> 6, cS1 = (g1 & 63) >> 1;

    // ---- fragment read offsets (swizzled byte offsets within a 16KB tile) ----
    int offA[8], offB[4];
    #pragma unroll
    for (int mf = 0; mf < 8; ++mf) {
        int row = wr * 128 + mf * 16 + ln15;
        offA[mf] = swz(row * 64 + hi * 16);
    }
    #pragma unroll
    for (int nf = 0; nf < 4; ++nf) {
        int row = wcn * 64 + nf * 16 + ln15;
        offB[nf] = swz(row * 64 + hi * 16);
    }

    f32x4 acc[8][4] = {};

    auto STAGE = [&](int kt, int buf) {
        const int t = kt >> 3;
        const int s = p ^ ((1 << t) >> 1);
        const unsigned short* ga = xb + (size_t)bm0 * INF + s * 256 + (kt & 7) * 32;
        const unsigned short* gb = wb + ((size_t)(t * 16 + s) << 16) + (kt & 7) * 32;
        char* lb = (char*)lds + buf * BUFB + wave * 1024;
        gl_lds16(ga + (size_t)rS0 * INF + cS0, lb);
        gl_lds16(ga + (size_t)rS1 * INF + cS1, lb + 8192);
        gl_lds16(gb + (size_t)rS0 * 256 + cS0, lb + 16384);
        gl_lds16(gb + (size_t)rS1 * 256 + cS1, lb + 16384 + 8192);
    };

    auto COMPUTE = [&](int buf) {
        const char* LA = (const char*)lds + buf * BUFB;
        const char* LB = LA + 16384;
        short8 fa[8], fb[4];
        #pragma unroll
        for (int nf = 0; nf < 4; ++nf) fb[nf] = *(const short8*)(LB + offB[nf]);
        #pragma unroll
        for (int mf = 0; mf < 8; ++mf) fa[mf] = *(const short8*)(LA + offA[mf]);
        __builtin_amdgcn_s_setprio(1);
        #pragma unroll
        for (int mf = 0; mf < 8; ++mf)
            #pragma unroll
            for (int nf = 0; nf < 4; ++nf)
                acc[mf][nf] = __builtin_amdgcn_mfma_f32_16x16x32_bf16(
                    fa[mf], fb[nf], acc[mf][nf], 0, 0, 0);
        __builtin_amdgcn_s_setprio(0);
    };

    // ---- prologue: fill pipeline 2 K-tiles deep ----
    STAGE(0, 0);
    STAGE(1, 1);

    // ---- main loop: issue kt+2, wait kt (vmcnt 8 = kt+1,kt+2 stay in flight) ----
    for (int kt = 0; kt < NKT - 2; ++kt) {
        STAGE(kt + 2, (kt + 2) % 3);
        asm volatile("s_waitcnt vmcnt(8)");
        __builtin_amdgcn_s_barrier();
        __builtin_amdgcn_sched_barrier(0);
        COMPUTE(kt % 3);
        __builtin_amdgcn_s_barrier();
        __builtin_amdgcn_sched_barrier(0);
    }
    // kt = NKT-2
    asm volatile("s_waitcnt vmcnt(4)");
    __builtin_amdgcn_s_barrier();
    __builtin_amdgcn_sched_barrier(0);
    COMPUTE((NKT - 2) % 3);
    __builtin_amdgcn_s_barrier();
    // kt = NKT-1
    asm volatile("s_waitcnt vmcnt(0)");
    __builtin_amdgcn_s_barrier();
    __builtin_amdgcn_sched_barrier(0);
    COMPUTE((NKT - 1) % 3);

    // ---- epilogue: C/D layout col = lane&15, row = (lane>>4)*4 + r ----
    const int col0 = p * 256 + wcn * 64;
    #pragma unroll
    for (int nf = 0; nf < 4; ++nf) {
        const int col = col0 + nf * 16 + ln15;
        const float bias = hb[col];
        #pragma unroll
        for (int mf = 0; mf < 8; ++mf) {
            #pragma unroll
            for (int r = 0; r < 4; ++r) {
                const int row = bm0 + wr * 128 + mf * 16 + hi * 4 + r;
                out[(size_t)row * 4096 + col] = acc[mf][nf][r] + bias;
            }
        }
    }
}

// ---------------- fallback (round-1 fused kernel) if ws too small ----------------
__global__ __launch_bounds__(256)
void hcl_mfma_fused(const float* __restrict__ x,
                    const float* __restrict__ hw,
                    const float* __restrict__ hb,
                    float* __restrict__ out)
{
    __shared__ unsigned short As[128][32];
    __shared__ unsigned short Bs[128][32];

    const int tid  = threadIdx.x;
    const int lane = tid & 63;
    const int wave = tid >> 6;
    const int wr   = wave >> 1, wc = wave & 1;

    const int bm0 = blockIdx.x * 128;
    const int p   = blockIdx.y >> 1;
    const int nh  = blockIdx.y & 1;

    f32x4 acc[4][4] = {};

    const int srow = tid >> 3;
    const int scol = (tid & 7) * 4;

    #pragma unroll
    for (int t = 0; t < 5; ++t) {
        const int mask = (t == 0) ? 0 : (1 << (t - 1));
        const int s = p ^ mask;
        const float* xchunk = x  + (size_t)bm0 * INF + s * 256;
        const float* wchunk = hw + ((size_t)(t * 16 + s) * 256 + nh * 128) * 256;

        for (int k8 = 0; k8 < 8; ++k8) {
            const int kc = k8 * 32;
            #pragma unroll
            for (int i = 0; i < 4; ++i) {
                const int row = i * 32 + srow;
                float4 fa = *(const float4*)(xchunk + (size_t)row * INF + kc + scol);
                float4 fb = *(const float4*)(wchunk + (size_t)row * 256 + kc + scol);
                ushort4 ua, ub;
                ua.x = f2bf(fa.x); ua.y = f2bf(fa.y);
                ua.z = f2bf(fa.z); ua.w = f2bf(fa.w);
                ub.x = f2bf(fb.x); ub.y = f2bf(fb.y);
                ub.z = f2bf(fb.z); ub.w = f2bf(fb.w);
                *(ushort4*)&As[row][scol] = ua;
                *(ushort4*)&Bs[row][scol] = ub;
            }
            __syncthreads();

            short8 a[4], b[4];
            #pragma unroll
            for (int mi = 0; mi < 4; ++mi)
                a[mi] = *(const short8*)&As[wr * 64 + mi * 16 + (lane & 15)][(lane >> 4) * 8];
            #pragma unroll
            for (int nj = 0; nj < 4; ++nj)
                b[nj] = *(const short8*)&Bs[wc * 64 + nj * 16 + (lane & 15)][(lane >> 4) * 8];

            #pragma unroll
            for (int mi = 0; mi < 4; ++mi)
                #pragma unroll
                for (int nj = 0; nj < 4; ++nj)
                    acc[mi][nj] = __builtin_amdgcn_mfma_f32_16x16x32_bf16(
                        a[mi], b[nj], acc[mi][nj], 0, 0, 0);

            __syncthreads();
        }
    }

    const int col0 = p * 256 + nh * 128 + wc * 64;
    #pragma unroll
    for (int nj = 0; nj < 4; ++nj) {
        const int col = col0 + nj * 16 + (lane & 15);
        const float bias = hb[col];
        #pragma unroll
        for (int mi = 0; mi < 4; ++mi) {
            #pragma unroll
            for (int r = 0; r < 4; ++r) {
                const int row = bm0 + wr * 64 + mi * 16 + (lane >> 4) * 4 + r;
                out[(size_t)row * 4096 + col] = acc[mi][nj][r] + bias;
            }
        }
    }
}

extern "C" void kernel_launch(void* const* d_in, const int* in_sizes, int n_in,
                              void* d_out, int out_size, void* d_ws, size_t ws_size,
                              hipStream_t stream) {
    const float* x  = (const float*)d_in[0];   // [8192, 4096]
    const float* hw = (const float*)d_in[1];   // [5, 16, 256, 256]
    const float* hb = (const float*)d_in[2];   // [4096]
    float* out = (float*)d_out;                // [8192, 4096]

    const size_t NX = 8192ull * 4096;
    const size_t NW = 5ull * 16 * 256 * 256;
    const size_t need = (NX + NW) * sizeof(unsigned short);

    if (ws_size >= need) {
        unsigned short* xb = (unsigned short*)d_ws;
        unsigned short* wb = xb + NX;
        cvt_bf16<<<2048, 256, 0, stream>>>(x, hw, xb, wb);
        dim3 grid(8192 / 256, 16);
        hcl_gemm8<<<grid, 512, 3 * BUFB, stream>>>(xb, wb, hb, out);
    } else {
        dim3 grid(8192 / 128, 32);
        hcl_mfma_fused<<<grid, 256, 0, stream>>>(x, hw, hb, out);
    }
}